// Round 1
// baseline (1018.183 us; speedup 1.0000x reference)
//
#include <hip/hip_runtime.h>
#include <cstddef>

#define DIM 128
#define T_LEN 4096
#define BATCH 32
#define L_CH 32
#define N_CH 128                    // T_LEN / L_CH
#define N_CHAINS (BATCH * N_CH)     // 4096
#define N_ROWS (BATCH * T_LEN)      // 131072

// ---------------- BU[m,i] = sum_k B[i,k] * u[m,k] ----------------
__global__ __launch_bounds__(128, 3) void k_bu(const float* __restrict__ u,
                                               const float* __restrict__ Bm,
                                               float* __restrict__ BU) {
    __shared__ __align__(16) float us[2][DIM];
    const int o = threadIdx.x;
    float br[DIM];
#pragma unroll
    for (int k = 0; k < DIM; k += 4) {
        const float4 v = *reinterpret_cast<const float4*>(&Bm[o * DIM + k]);
        br[k] = v.x; br[k + 1] = v.y; br[k + 2] = v.z; br[k + 3] = v.w;
    }
    const int rpb = N_ROWS / gridDim.x;
    const int m0 = blockIdx.x * rpb;
    us[0][o] = u[(size_t)m0 * DIM + o];
    __syncthreads();
#pragma unroll 1
    for (int r = 0; r < rpb; ++r) {
        const int m = m0 + r;
        if (r + 1 < rpb) us[(r + 1) & 1][o] = u[(size_t)(m + 1) * DIM + o];
        const float* xr = us[r & 1];
        float a0 = 0.f, a1 = 0.f, a2 = 0.f, a3 = 0.f;
#pragma unroll
        for (int k = 0; k < DIM; k += 4) {
            const float4 xv = *reinterpret_cast<const float4*>(&xr[k]);
            a0 = fmaf(br[k],     xv.x, a0);
            a1 = fmaf(br[k + 1], xv.y, a1);
            a2 = fmaf(br[k + 2], xv.z, a2);
            a3 = fmaf(br[k + 3], xv.w, a3);
        }
        BU[(size_t)m * DIM + o] = (a0 + a1) + (a2 + a3);
        __syncthreads();
    }
}

// ---------------- O = X * Y (128x128 * 128x128), row-major ----------------
__global__ __launch_bounds__(256, 2) void k_mm128(const float* __restrict__ X,
                                                  const float* __restrict__ Y,
                                                  float* __restrict__ O) {
    __shared__ __align__(16) float Ys[DIM][DIM];
    const int t = threadIdx.x;
#pragma unroll
    for (int i = 0; i < 16; ++i) {
        const int j = t + i * 256;
        reinterpret_cast<float4*>(&Ys[0][0])[j] = reinterpret_cast<const float4*>(Y)[j];
    }
    const int r = blockIdx.x * 32 + (t >> 3);
    const int c0 = (t & 7) * 16;
    float xr[DIM];
#pragma unroll
    for (int k = 0; k < DIM; k += 4) {
        const float4 v = *reinterpret_cast<const float4*>(&X[r * DIM + k]);
        xr[k] = v.x; xr[k + 1] = v.y; xr[k + 2] = v.z; xr[k + 3] = v.w;
    }
    __syncthreads();
    float acc[16];
#pragma unroll
    for (int j = 0; j < 16; ++j) acc[j] = 0.f;
#pragma unroll
    for (int k = 0; k < DIM; ++k) {
        const float xv = xr[k];
#pragma unroll
        for (int j = 0; j < 16; j += 4) {
            const float4 yv = *reinterpret_cast<const float4*>(&Ys[k][c0 + j]);
            acc[j + 0] = fmaf(xv, yv.x, acc[j + 0]);
            acc[j + 1] = fmaf(xv, yv.y, acc[j + 1]);
            acc[j + 2] = fmaf(xv, yv.z, acc[j + 2]);
            acc[j + 3] = fmaf(xv, yv.w, acc[j + 3]);
        }
    }
#pragma unroll
    for (int j = 0; j < 16; j += 4) {
        *reinterpret_cast<float4*>(&O[r * DIM + c0 + j]) =
            make_float4(acc[j], acc[j + 1], acc[j + 2], acc[j + 3]);
    }
}

// ---------------- pass 1: chunk-local scan from 0, emit end state V ----------------
__global__ __launch_bounds__(128, 3) void k_scan1(const float* __restrict__ Am,
                                                  const float* __restrict__ BU,
                                                  float* __restrict__ V) {
    __shared__ __align__(16) float xs[2][DIM];
    const int i = threadIdx.x;
    const int chain = blockIdx.x;            // b*128 + c ; global row = 32*chain
    float ar[DIM];
#pragma unroll
    for (int k = 0; k < DIM; k += 4) {
        const float4 v = *reinterpret_cast<const float4*>(&Am[i * DIM + k]);
        ar[k] = v.x; ar[k + 1] = v.y; ar[k + 2] = v.z; ar[k + 3] = v.w;
    }
    const size_t base = (size_t)chain * L_CH * DIM;
    xs[0][i] = 0.f;
    __syncthreads();
    float bu = BU[base + i];
    float x1 = 0.f;
#pragma unroll 1
    for (int r = 0; r < L_CH; ++r) {
        float bu_next = 0.f;
        if (r + 1 < L_CH) bu_next = BU[base + (size_t)(r + 1) * DIM + i];
        const float* xc = xs[r & 1];
        float a0 = 0.f, a1 = 0.f, a2 = 0.f, a3 = 0.f;
#pragma unroll
        for (int k = 0; k < DIM; k += 4) {
            const float4 xv = *reinterpret_cast<const float4*>(&xc[k]);
            a0 = fmaf(ar[k],     xv.x, a0);
            a1 = fmaf(ar[k + 1], xv.y, a1);
            a2 = fmaf(ar[k + 2], xv.z, a2);
            a3 = fmaf(ar[k + 3], xv.w, a3);
        }
        x1 = (a0 + a1) + (a2 + a3) + bu;
        bu = bu_next;
        xs[(r + 1) & 1][i] = x1;
        __syncthreads();
    }
    V[(size_t)chain * DIM + i] = x1;
}

// ---------------- boundary combine: s_c = A32 * s_{c-1} + v_{c-1} ----------------
__global__ __launch_bounds__(128, 3) void k_comb(const float* __restrict__ A32,
                                                 const float* __restrict__ V,
                                                 float* __restrict__ S) {
    __shared__ __align__(16) float ss[2][DIM];
    const int i = threadIdx.x;
    const int b = blockIdx.x;
    float ar[DIM];
#pragma unroll
    for (int k = 0; k < DIM; k += 4) {
        const float4 v = *reinterpret_cast<const float4*>(&A32[i * DIM + k]);
        ar[k] = v.x; ar[k + 1] = v.y; ar[k + 2] = v.z; ar[k + 3] = v.w;
    }
    S[(size_t)b * N_CH * DIM + i] = 0.f;    // s_0 = 0
    ss[0][i] = 0.f;
    __syncthreads();
    float vn = V[(size_t)b * N_CH * DIM + i];   // V[b][0]
#pragma unroll 1
    for (int c = 1; c < N_CH; ++c) {
        float vn_next = 0.f;
        if (c < N_CH - 1) vn_next = V[((size_t)b * N_CH + c) * DIM + i];
        const float* sc = ss[(c - 1) & 1];
        float a0 = 0.f, a1 = 0.f, a2 = 0.f, a3 = 0.f;
#pragma unroll
        for (int k = 0; k < DIM; k += 4) {
            const float4 xv = *reinterpret_cast<const float4*>(&sc[k]);
            a0 = fmaf(ar[k],     xv.x, a0);
            a1 = fmaf(ar[k + 1], xv.y, a1);
            a2 = fmaf(ar[k + 2], xv.z, a2);
            a3 = fmaf(ar[k + 3], xv.w, a3);
        }
        const float s1 = (a0 + a1) + (a2 + a3) + vn;
        vn = vn_next;
        S[((size_t)b * N_CH + c) * DIM + i] = s1;
        ss[c & 1][i] = s1;
        __syncthreads();
    }
}

// ---------------- pass 2: scan from true s_c, write x(t+1) to out ----------------
__global__ __launch_bounds__(128, 3) void k_scan2(const float* __restrict__ Am,
                                                  const float* __restrict__ BU,
                                                  const float* __restrict__ S,
                                                  float* __restrict__ xout) {
    __shared__ __align__(16) float xs[2][DIM];
    const int i = threadIdx.x;
    const int chain = blockIdx.x;
    float ar[DIM];
#pragma unroll
    for (int k = 0; k < DIM; k += 4) {
        const float4 v = *reinterpret_cast<const float4*>(&Am[i * DIM + k]);
        ar[k] = v.x; ar[k + 1] = v.y; ar[k + 2] = v.z; ar[k + 3] = v.w;
    }
    const size_t base = (size_t)chain * L_CH * DIM;
    xs[0][i] = S[(size_t)chain * DIM + i];
    __syncthreads();
    float bu = BU[base + i];
#pragma unroll 1
    for (int r = 0; r < L_CH; ++r) {
        float bu_next = 0.f;
        if (r + 1 < L_CH) bu_next = BU[base + (size_t)(r + 1) * DIM + i];
        const float* xc = xs[r & 1];
        float a0 = 0.f, a1 = 0.f, a2 = 0.f, a3 = 0.f;
#pragma unroll
        for (int k = 0; k < DIM; k += 4) {
            const float4 xv = *reinterpret_cast<const float4*>(&xc[k]);
            a0 = fmaf(ar[k],     xv.x, a0);
            a1 = fmaf(ar[k + 1], xv.y, a1);
            a2 = fmaf(ar[k + 2], xv.z, a2);
            a3 = fmaf(ar[k + 3], xv.w, a3);
        }
        const float x1 = (a0 + a1) + (a2 + a3) + bu;
        bu = bu_next;
        xout[base + (size_t)r * DIM + i] = x1;   // x(t+1) at t = 32*chain + r
        xs[(r + 1) & 1][i] = x1;
        __syncthreads();
    }
}

// ---------------- epilogue: y[m] = C*x[m] + D*u[m], in place on d_out ----------------
__global__ __launch_bounds__(256, 3) void k_y(const float* __restrict__ u,
                                              const float* __restrict__ Cm,
                                              const float* __restrict__ Dm,
                                              float* __restrict__ yx) {
    __shared__ __align__(16) float xsb[2][DIM];
    __shared__ __align__(16) float usb[2][DIM];
    __shared__ float ps[256];
    const int t = threadIdx.x;
    const int o = t & (DIM - 1);
    const int part = t >> 7;                 // 0: C*x partial, 1: D*u partial
    const float* __restrict__ M = part ? Dm : Cm;
    float mr[DIM];
#pragma unroll
    for (int k = 0; k < DIM; k += 4) {
        const float4 v = *reinterpret_cast<const float4*>(&M[o * DIM + k]);
        mr[k] = v.x; mr[k + 1] = v.y; mr[k + 2] = v.z; mr[k + 3] = v.w;
    }
    const int rpb = N_ROWS / gridDim.x;
    const size_t m0 = (size_t)blockIdx.x * rpb;
    if (part == 0) xsb[0][o] = yx[m0 * DIM + o];
    else           usb[0][o] = u[m0 * DIM + o];
    __syncthreads();
#pragma unroll 1
    for (int r = 0; r < rpb; ++r) {
        const size_t m = m0 + r;
        if (r + 1 < rpb) {
            if (part == 0) xsb[(r + 1) & 1][o] = yx[(m + 1) * DIM + o];
            else           usb[(r + 1) & 1][o] = u[(m + 1) * DIM + o];
        }
        const float* in = part ? usb[r & 1] : xsb[r & 1];
        float a0 = 0.f, a1 = 0.f, a2 = 0.f, a3 = 0.f;
#pragma unroll
        for (int k = 0; k < DIM; k += 4) {
            const float4 xv = *reinterpret_cast<const float4*>(&in[k]);
            a0 = fmaf(mr[k],     xv.x, a0);
            a1 = fmaf(mr[k + 1], xv.y, a1);
            a2 = fmaf(mr[k + 2], xv.z, a2);
            a3 = fmaf(mr[k + 3], xv.w, a3);
        }
        ps[t] = (a0 + a1) + (a2 + a3);
        __syncthreads();
        if (part == 0) yx[m * DIM + o] = ps[o] + ps[o + DIM];
        __syncthreads();
    }
}

extern "C" void kernel_launch(void* const* d_in, const int* in_sizes, int n_in,
                              void* d_out, int out_size, void* d_ws, size_t ws_size,
                              hipStream_t stream) {
    const float* u  = (const float*)d_in[0];   // [32,4096,128]
    const float* Am = (const float*)d_in[1];   // [128,128]
    const float* Bm = (const float*)d_in[2];
    const float* Cm = (const float*)d_in[3];
    const float* Dm = (const float*)d_in[4];
    float* out = (float*)d_out;                // [32,4096,128] fp32

    // ws layout (floats): BU 16.7M | V 0.5M | S 0.5M | A^2,A^4,A^8,A^16,A^32
    float* ws  = (float*)d_ws;
    float* BU  = ws;
    float* V   = BU + (size_t)N_ROWS * DIM;
    float* S   = V + (size_t)N_CHAINS * DIM;
    float* P2  = S + (size_t)N_CHAINS * DIM;
    float* P4  = P2 + DIM * DIM;
    float* P8  = P4 + DIM * DIM;
    float* P16 = P8 + DIM * DIM;
    float* P32 = P16 + DIM * DIM;

    hipLaunchKernelGGL(k_bu, dim3(1024), dim3(128), 0, stream, u, Bm, BU);
    hipLaunchKernelGGL(k_mm128, dim3(4), dim3(256), 0, stream, Am, Am, P2);
    hipLaunchKernelGGL(k_mm128, dim3(4), dim3(256), 0, stream, P2, P2, P4);
    hipLaunchKernelGGL(k_mm128, dim3(4), dim3(256), 0, stream, P4, P4, P8);
    hipLaunchKernelGGL(k_mm128, dim3(4), dim3(256), 0, stream, P8, P8, P16);
    hipLaunchKernelGGL(k_mm128, dim3(4), dim3(256), 0, stream, P16, P16, P32);
    hipLaunchKernelGGL(k_scan1, dim3(N_CHAINS), dim3(128), 0, stream, Am, BU, V);
    hipLaunchKernelGGL(k_comb, dim3(BATCH), dim3(128), 0, stream, P32, V, S);
    hipLaunchKernelGGL(k_scan2, dim3(N_CHAINS), dim3(128), 0, stream, Am, BU, S, out);
    hipLaunchKernelGGL(k_y, dim3(2048), dim3(256), 0, stream, u, Cm, Dm, out);
}